// Round 2
// baseline (625.228 us; speedup 1.0000x reference)
//
#include <hip/hip_runtime.h>

typedef float  f32x4 __attribute__((ext_vector_type(4)));
typedef short  s16x8 __attribute__((ext_vector_type(8)));
typedef short  s16x4 __attribute__((ext_vector_type(4)));

#define B_   16
#define S_   2048
#define D_   512
#define BM   32
#define BN   256
#define PTS  264   // padded P^T row stride (shorts): 256 + 8 -> 528 B, 132 dwords == 4 mod 32
#define C1   0.06376279834938389f   // log2(e)/sqrt(512): scores pre-scaled into base-2 domain

__device__ __forceinline__ short f2bf(float f){
    unsigned u = __float_as_uint(f);
    u += 0x7fffu + ((u >> 16) & 1u);   // RNE
    return (short)(u >> 16);
}
__device__ __forceinline__ float hmax4(f32x4 v){
    return fmaxf(fmaxf(v[0],v[1]), fmaxf(v[2],v[3]));
}
__device__ __forceinline__ f32x4 max4(f32x4 a, f32x4 b){
    f32x4 r; r[0]=fmaxf(a[0],b[0]); r[1]=fmaxf(a[1],b[1]);
             r[2]=fmaxf(a[2],b[2]); r[3]=fmaxf(a[3],b[3]); return r;
}

// ---------------- fused prep: K fp32->bf16 [B][S][D]; V fp32 -> bf16 VT [B][D][S] ----------------
__global__ void prep_kernel(const float* __restrict__ k, const float* __restrict__ v,
                            short* __restrict__ kb, short* __restrict__ vt){
    __shared__ float tile[64][65];
    int b  = blockIdx.z;
    int s0 = blockIdx.x * 64;
    int d0 = blockIdx.y * 64;
    int t  = threadIdx.x;          // 256
    int r  = t >> 2;               // 0..63
    int c4 = (t & 3) * 16;         // 0,16,32,48
    long off = ((long)b*S_ + s0 + r)*D_ + d0 + c4;

    // K: straight cast, row-major
    {
        const float4* ksrc = (const float4*)(k + off);
        float4 a0 = ksrc[0], a1 = ksrc[1], a2 = ksrc[2], a3 = ksrc[3];
        s16x8 w0, w1;
        w0[0]=f2bf(a0.x); w0[1]=f2bf(a0.y); w0[2]=f2bf(a0.z); w0[3]=f2bf(a0.w);
        w0[4]=f2bf(a1.x); w0[5]=f2bf(a1.y); w0[6]=f2bf(a1.z); w0[7]=f2bf(a1.w);
        w1[0]=f2bf(a2.x); w1[1]=f2bf(a2.y); w1[2]=f2bf(a2.z); w1[3]=f2bf(a2.w);
        w1[4]=f2bf(a3.x); w1[5]=f2bf(a3.y); w1[6]=f2bf(a3.z); w1[7]=f2bf(a3.w);
        short* dst = kb + off;
        *(s16x8*)dst       = w0;
        *(s16x8*)(dst + 8) = w1;
    }
    // V: transpose via LDS
    {
        const float4* vsrc = (const float4*)(v + off);
        float4 a0 = vsrc[0], a1 = vsrc[1], a2 = vsrc[2], a3 = vsrc[3];
        tile[r][c4+ 0]=a0.x; tile[r][c4+ 1]=a0.y; tile[r][c4+ 2]=a0.z; tile[r][c4+ 3]=a0.w;
        tile[r][c4+ 4]=a1.x; tile[r][c4+ 5]=a1.y; tile[r][c4+ 6]=a1.z; tile[r][c4+ 7]=a1.w;
        tile[r][c4+ 8]=a2.x; tile[r][c4+ 9]=a2.y; tile[r][c4+10]=a2.z; tile[r][c4+11]=a2.w;
        tile[r][c4+12]=a3.x; tile[r][c4+13]=a3.y; tile[r][c4+14]=a3.z; tile[r][c4+15]=a3.w;
    }
    __syncthreads();
    s16x8 w0, w1;
    #pragma unroll
    for (int i = 0; i < 8; ++i)  w0[i] = f2bf(tile[c4+i][r]);
    #pragma unroll
    for (int i = 0; i < 8; ++i)  w1[i] = f2bf(tile[c4+8+i][r]);
    short* dst = vt + ((long)b*D_ + d0 + r)*S_ + s0 + c4;
    *(s16x8*)dst       = w0;
    *(s16x8*)(dst + 8) = w1;
}

// ---------------- flash attention, S^T formulation ----------------
// QK: compute S^T = K_tile @ Q^T. C-layout => col = q (lane&15), row = kv (quad*4+reg):
//   - per-q stats are in-lane over regs + 2 quad shuffles (no 4-stage f32x4 shuffles)
//   - P^T written to LDS as packed ds_write_b64 (4/iter vs 64 scalar b16)
//   - PV reads P^T rows contiguously (b128); O comes out in [q][d] layout
// Wave split: QK N... kv-split (wave w owns kv 32w..32w+31, K frags from global);
// PV d-split (wave w owns d 64w..64w+63, V frags from global VT). 2 barriers/iter.
__global__ __launch_bounds__(512, 4) void flash_kernel(
    const float* __restrict__ q, const short* __restrict__ kb,
    const short* __restrict__ vt, float* __restrict__ out)
{
    __shared__ __align__(16) short q_lds[BM*D_];    // 32 KB, 8-short granules xor-swizzled by row&7
    __shared__ __align__(16) short pt_lds[BM*PTS];  // 16.5 KB, [q][kv] padded rows
    __shared__ float pmax[BM][8];
    __shared__ float psum[BM][8];

    // block -> (batch, qtile): XCD-affinity on batch, heavy q-tiles first
    int bx = blockIdx.x;
    int lo = bx & 7;
    int hi = bx >> 3;
    int batch = 2*lo + (hi & 1);
    int t = hi >> 1;
    int qt = (t < 32) ? (63 - t) : (t - 32);
    int q0 = qt * BM;

    int tid  = threadIdx.x;
    int w    = tid >> 6;
    int lane = tid & 63;
    int m    = lane & 15;
    int quad = lane >> 4;

    // ---- stage Q (fp32 -> bf16, swizzled) ----
    {
        int r  = tid >> 4;            // 0..31
        int cb = (tid & 15) << 5;     // 32 floats per thread
        const float* qrow = q + ((long)batch*S_ + q0 + r)*D_;
        #pragma unroll
        for (int gi = 0; gi < 4; ++gi){
            int c = cb + gi*8;
            float4 f0 = *(const float4*)(qrow + c);
            float4 f1 = *(const float4*)(qrow + c + 4);
            s16x8 vv;
            vv[0]=f2bf(f0.x); vv[1]=f2bf(f0.y); vv[2]=f2bf(f0.z); vv[3]=f2bf(f0.w);
            vv[4]=f2bf(f1.x); vv[5]=f2bf(f1.y); vv[6]=f2bf(f1.z); vv[7]=f2bf(f1.w);
            int g = c >> 3;
            *(s16x8*)&q_lds[r*D_ + (((g ^ (r & 7)) & 63) << 3)] = vv;
        }
    }
    __syncthreads();

    f32x4 o_acc[2][4];                 // rows q = mt*16+quad*4+rr ; cols d = w*64+nt*16+m
    #pragma unroll
    for (int a = 0; a < 2; ++a)
        #pragma unroll
        for (int b2 = 0; b2 < 4; ++b2) o_acc[a][b2] = (f32x4)0.0f;
    f32x4 m_row[2], l_row[2];          // state per O-row (base-2 domain)
    m_row[0] = (f32x4)(-1e30f); m_row[1] = (f32x4)(-1e30f);
    l_row[0] = (f32x4)0.0f;     l_row[1] = (f32x4)0.0f;
    float m_col[2] = {-1e30f, -1e30f}; // state per P-col q = nt*16+m (same values, col view)

    const short* kbb = kb + (long)batch*S_*D_;
    const short* vtb = vt + (long)batch*D_*S_;
    int jmax = q0 >> 8;

    for (int j = 0; j <= jmax; ++j){
        int kbase = j << 8;

        // ---------- S^T = K @ Q^T : acc[mtKV][ntQ], row=kv, col=q ----------
        f32x4 acc[2][2];
        acc[0][0]=(f32x4)0.0f; acc[0][1]=(f32x4)0.0f;
        acc[1][0]=(f32x4)0.0f; acc[1][1]=(f32x4)0.0f;
        const short* kp0 = kbb + ((long)(kbase + w*32 + m))*D_ + quad*8;
        #pragma unroll
        for (int ks = 0; ks < 16; ++ks){
            const short* kp = kp0 + ks*32;
            s16x8 ka0 = *(const s16x8*)kp;              // kv rows w*32+m
            s16x8 ka1 = *(const s16x8*)(kp + 16*D_);    // kv rows w*32+16+m
            int gq = ((ks*4 + quad) ^ (m & 7)) << 3;
            s16x8 qb0 = *(const s16x8*)&q_lds[ m      *D_ + gq];
            s16x8 qb1 = *(const s16x8*)&q_lds[(16 + m)*D_ + gq];
            acc[0][0] = __builtin_amdgcn_mfma_f32_16x16x32_bf16(ka0, qb0, acc[0][0], 0,0,0);
            acc[0][1] = __builtin_amdgcn_mfma_f32_16x16x32_bf16(ka0, qb1, acc[0][1], 0,0,0);
            acc[1][0] = __builtin_amdgcn_mfma_f32_16x16x32_bf16(ka1, qb0, acc[1][0], 0,0,0);
            acc[1][1] = __builtin_amdgcn_mfma_f32_16x16x32_bf16(ka1, qb1, acc[1][1], 0,0,0);
        }

        // ---------- scale into base-2 + causal mask (row=kv, col=q) ----------
        if (j == jmax){
            #pragma unroll
            for (int mt = 0; mt < 2; ++mt)
                #pragma unroll
                for (int nt = 0; nt < 2; ++nt){
                    int qg = q0 + nt*16 + m;
                    #pragma unroll
                    for (int rr = 0; rr < 4; ++rr){
                        int kvg = kbase + w*32 + mt*16 + quad*4 + rr;
                        float s = acc[mt][nt][rr] * C1;
                        acc[mt][nt][rr] = (kvg > qg) ? -1e30f : s;
                    }
                }
        } else {
            #pragma unroll
            for (int mt = 0; mt < 2; ++mt)
                #pragma unroll
                for (int nt = 0; nt < 2; ++nt)
                    #pragma unroll
                    for (int rr = 0; rr < 4; ++rr)
                        acc[mt][nt][rr] *= C1;
        }

        // ---------- per-column (q) max over this wave's 32 kv ----------
        #pragma unroll
        for (int nt = 0; nt < 2; ++nt){
            float cm = fmaxf(hmax4(acc[0][nt]), hmax4(acc[1][nt]));
            cm = fmaxf(cm, __shfl_xor(cm, 16));
            cm = fmaxf(cm, __shfl_xor(cm, 32));
            if (quad == 0) pmax[nt*16 + m][w] = cm;
        }
        __syncthreads();

        // ---------- row stats: new max, alpha, rescale O/l ----------
        f32x4 alpha[2];
        #pragma unroll
        for (int mt = 0; mt < 2; ++mt){
            #pragma unroll
            for (int rr = 0; rr < 4; ++rr){
                int row = mt*16 + quad*4 + rr;
                f32x4 p0 = *(const f32x4*)&pmax[row][0];
                f32x4 p1 = *(const f32x4*)&pmax[row][4];
                float mx = hmax4(max4(p0, p1));
                float mn = fmaxf(m_row[mt][rr], mx);
                alpha[mt][rr] = exp2f(m_row[mt][rr] - mn);
                m_row[mt][rr] = mn;
            }
            l_row[mt] *= alpha[mt];
            #pragma unroll
            for (int nt = 0; nt < 4; ++nt) o_acc[mt][nt] *= alpha[mt];
        }
        // ---------- col stats (same values, column view for exp) ----------
        float mcn[2];
        #pragma unroll
        for (int nt = 0; nt < 2; ++nt){
            int row = nt*16 + m;
            f32x4 p0 = *(const f32x4*)&pmax[row][0];
            f32x4 p1 = *(const f32x4*)&pmax[row][4];
            float mx = hmax4(max4(p0, p1));
            mcn[nt] = fmaxf(m_col[nt], mx);
            m_col[nt] = mcn[nt];
        }

        // ---------- P = exp2, packed b64 write of P^T, column sums ----------
        #pragma unroll
        for (int nt = 0; nt < 2; ++nt){
            float cs = 0.0f;
            #pragma unroll
            for (int mt = 0; mt < 2; ++mt){
                s16x4 pk;
                #pragma unroll
                for (int rr = 0; rr < 4; ++rr){
                    float p = exp2f(acc[mt][nt][rr] - mcn[nt]);
                    cs += p;
                    pk[rr] = f2bf(p);
                }
                *(s16x4*)&pt_lds[(nt*16 + m)*PTS + w*32 + mt*16 + quad*4] = pk;
            }
            cs += __shfl_xor(cs, 16);
            cs += __shfl_xor(cs, 32);
            if (quad == 0) psum[nt*16 + m][w] = cs;
        }
        __syncthreads();

        // ---------- l update ----------
        #pragma unroll
        for (int mt = 0; mt < 2; ++mt)
            #pragma unroll
            for (int rr = 0; rr < 4; ++rr){
                int row = mt*16 + quad*4 + rr;
                f32x4 s0 = *(const f32x4*)&psum[row][0];
                f32x4 s1 = *(const f32x4*)&psum[row][4];
                f32x4 ss = s0 + s1;
                l_row[mt][rr] += (ss[0]+ss[1]) + (ss[2]+ss[3]);
            }

        // ---------- PV : O[q][d] += P^T-rows (LDS, contiguous) @ V (global VT) ----------
        const short* vp0 = vtb + ((long)(w*64 + m))*S_ + kbase + quad*8;
        #pragma unroll
        for (int ks = 0; ks < 8; ++ks){
            s16x8 pa0 = *(const s16x8*)&pt_lds[ m      *PTS + ks*32 + quad*8];
            s16x8 pa1 = *(const s16x8*)&pt_lds[(16 + m)*PTS + ks*32 + quad*8];
            const short* vp = vp0 + ks*32;
            s16x8 vb0 = *(const s16x8*)vp;
            s16x8 vb1 = *(const s16x8*)(vp + 16*S_);
            s16x8 vb2 = *(const s16x8*)(vp + 32*S_);
            s16x8 vb3 = *(const s16x8*)(vp + 48*S_);
            o_acc[0][0] = __builtin_amdgcn_mfma_f32_16x16x32_bf16(pa0, vb0, o_acc[0][0], 0,0,0);
            o_acc[0][1] = __builtin_amdgcn_mfma_f32_16x16x32_bf16(pa0, vb1, o_acc[0][1], 0,0,0);
            o_acc[0][2] = __builtin_amdgcn_mfma_f32_16x16x32_bf16(pa0, vb2, o_acc[0][2], 0,0,0);
            o_acc[0][3] = __builtin_amdgcn_mfma_f32_16x16x32_bf16(pa0, vb3, o_acc[0][3], 0,0,0);
            o_acc[1][0] = __builtin_amdgcn_mfma_f32_16x16x32_bf16(pa1, vb0, o_acc[1][0], 0,0,0);
            o_acc[1][1] = __builtin_amdgcn_mfma_f32_16x16x32_bf16(pa1, vb1, o_acc[1][1], 0,0,0);
            o_acc[1][2] = __builtin_amdgcn_mfma_f32_16x16x32_bf16(pa1, vb2, o_acc[1][2], 0,0,0);
            o_acc[1][3] = __builtin_amdgcn_mfma_f32_16x16x32_bf16(pa1, vb3, o_acc[1][3], 0,0,0);
        }
        // next iteration's first barrier protects pt_lds/pmax/psum reuse
    }

    // ---------- epilogue: O /= l, store fp32 (O already [q][d]) ----------
    float* ob = out + ((long)batch*S_ + q0)*D_ + w*64;
    #pragma unroll
    for (int mt = 0; mt < 2; ++mt){
        f32x4 inv;
        #pragma unroll
        for (int rr = 0; rr < 4; ++rr) inv[rr] = 1.0f / l_row[mt][rr];
        #pragma unroll
        for (int nt = 0; nt < 4; ++nt){
            f32x4 vv = o_acc[mt][nt] * inv;
            #pragma unroll
            for (int rr = 0; rr < 4; ++rr)
                ob[(long)(mt*16 + quad*4 + rr)*D_ + nt*16 + m] = vv[rr];
        }
    }
}

extern "C" void kernel_launch(void* const* d_in, const int* in_sizes, int n_in,
                              void* d_out, int out_size, void* d_ws, size_t ws_size,
                              hipStream_t stream) {
    const float* q = (const float*)d_in[0];
    const float* k = (const float*)d_in[1];
    const float* v = (const float*)d_in[2];
    float* out = (float*)d_out;
    short* kbb = (short*)d_ws;                       // 32 MiB bf16 K
    short* vtb = kbb + (size_t)B_*S_*D_;             // 32 MiB bf16 V^T
    prep_kernel<<<dim3(S_/64, D_/64, B_), 256, 0, stream>>>(k, v, kbb, vtb);
    flash_kernel<<<1024, 512, 0, stream>>>(q, kbb, vtb, out);
}